// Round 7
// baseline (446.112 us; speedup 1.0000x reference)
//
#include <hip/hip_runtime.h>
#include <stdint.h>

// Problem constants (from reference)
#define N_CLASSES  10
#define N_TREES    4000
#define DEPTH      6
#define N_INTERNAL 63
#define N_FEATURES 128
#define BATCH      32768
#define LR         0.1f

// Kernel config (R19 = R13 champion geometry + OPAQUE top-node offload).
// R13 (243us) is DS-pipe-saturated: 12 b64 + 12 b32 per wave-tile.
// R15/R16/R17 all tried to move depths 0-2 off the DS pipe and all failed
// the same way: compiler-visible loads from __restrict__-const memory get
// rematerialized/sunk to the use point (VGPR stayed 52), exposing L2
// latency per tile. R19 makes the prefetch COMPILER-OPAQUE:
//  - top nodes + leaves loaded by inline-asm global_load (named ext_vector
//    outputs; volatile asm defs can't be remat'd, sunk, or scratched)
//  - all in-loop VMEM manual -> exact FIFO: 12 ops/body (lv2+stage2+ldt8);
//    guard vmcnt(12) at body b drains exactly body (b-2)'s batch
//  - leaves consumed +2 bodies, parity-split regs (no copy of in-flight)
//  - after each guard: sched_barrier(0) + no-op asm "+v" re-def of the
//    parity's regs (rule-18 fence: nothing hoists above the wait)
// DS demand: 6 b64 + 12 b32 ~= 112 cyc/wave-tile -> 448K cyc/CU ~= 187us.
#define BLOCK       256
#define SAMPLES_PB  32
#define T_TILE      16                      // trees per LDS tile (8 KB int2 nodes)
#define N_TILES     (N_TREES / T_TILE)      // 250
#define TILES_PER_CLASS ((N_TREES / N_CLASSES) / T_TILE)   // 25
#define SUMS_STRIDE 11

// prep grid split
#define XPOSE_BLOCKS (BATCH / SAMPLES_PB)           // 1024
#define PACK_BLOCKS  ((N_TREES * 64) / BLOCK)       // 1000

// ws layout (unchanged):
//   [0, 2.048MB)        nodes by slot, interleaved int2 (feat, thr_bits), 64/tree
//   [2.048MB, 3.072MB)  leaves (64 f32/tree), class-grouped slots
//   [3.072MB, 19.85MB)  x^T: [N_FEATURES][BATCH] f32 (DMA-friendly staging)
#define WS_NODES_BYTES  ((size_t)N_TREES * 64 * 8)
#define WS_LEAVES_BYTES ((size_t)N_TREES * 64 * 4)
#define WS_XT_BYTES     ((size_t)N_FEATURES * BATCH * 4)

using i32x4 = __attribute__((ext_vector_type(4))) int;
using i32x2 = __attribute__((ext_vector_type(2))) int;

// Opaque global loads: volatile asm, named register outputs.
#define GLD_X4(dst, base, OFFSTR)                                              \
    asm volatile("global_load_dwordx4 %0, %1, off offset:" OFFSTR              \
                 : "=v"(dst) : "v"(base))
#define GLD_X2(dst, base, OFFSTR)                                              \
    asm volatile("global_load_dwordx2 %0, %1, off offset:" OFFSTR              \
                 : "=v"(dst) : "v"(base))
#define GLD_DW(dst, base)                                                      \
    asm volatile("global_load_dword %0, %1, off" : "=v"(dst) : "v"(base))

// Top-7 nodes of this thread's 2 trees for tile T_ into parity-P_ regs.
// One 64-bit base; tree j*2 at offsets 0..48, tree j*2+1 at 512..560.
#define LDT_ASM(T_, P_)                                                        \
    do {                                                                       \
        const char* tb__ = (const char*)pnodes                                 \
            + (size_t)((T_) * T_TILE + j * 2) * 512;                           \
        GLD_X4(t##P_##0a, tb__, "0");                                          \
        GLD_X4(t##P_##0b, tb__, "16");                                         \
        GLD_X4(t##P_##0c, tb__, "32");                                         \
        GLD_X2(t##P_##0d, tb__, "48");                                         \
        GLD_X4(t##P_##1a, tb__, "512");                                        \
        GLD_X4(t##P_##1b, tb__, "528");                                        \
        GLD_X4(t##P_##1c, tb__, "544");                                        \
        GLD_X2(t##P_##1d, tb__, "560");                                        \
    } while (0)

// Rule-18 fence: re-define the parity's asm-loaded regs AFTER the guard so
// no use (or address calc) can hoist above the s_waitcnt.
#define REG_FENCE(P_)                                                          \
    asm volatile("" : "+v"(t##P_##0a), "+v"(t##P_##0b), "+v"(t##P_##0c),       \
                      "+v"(t##P_##0d), "+v"(t##P_##1a), "+v"(t##P_##1b),       \
                      "+v"(t##P_##1c), "+v"(t##P_##1d),                        \
                      "+v"(lv##P_##0), "+v"(lv##P_##1))

// Phase A for one tree from regs A(n0,n1) B(n2,n3) C(n4,n5) D(n6):
// layout per reg: [feat, thr_bits, feat, thr_bits].
#define PHASE_A(A_, B_, C_, D_, ORES_)                                         \
    do {                                                                       \
        float xa_ = xs[A_[0] * SAMPLES_PB + sLocal];                           \
        int b0_ = xa_ > __int_as_float(A_[1]);                                 \
        int f1_ = b0_ ? B_[0] : A_[2];                                         \
        int t1_ = b0_ ? B_[1] : A_[3];                                         \
        float xb_ = xs[f1_ * SAMPLES_PB + sLocal];                             \
        int b1_ = xb_ > __int_as_float(t1_);                                   \
        int fA_ = b0_ ? C_[2] : B_[2];   /* n5 : n3 */                         \
        int tA_ = b0_ ? C_[3] : B_[3];                                         \
        int fB_ = b0_ ? D_[0] : C_[0];   /* n6 : n4 */                         \
        int tB_ = b0_ ? D_[1] : C_[1];                                         \
        int f2_ = b1_ ? fB_ : fA_;                                             \
        int t2_ = b1_ ? tB_ : tA_;                                             \
        float xc_ = xs[f2_ * SAMPLES_PB + sLocal];                             \
        int b2_ = xc_ > __int_as_float(t2_);                                   \
        ORES_ = 7 + 4 * b0_ + 2 * b1_ + b2_;                                   \
    } while (0)

// One tile body. GUARDSTR is the literal vmcnt count.
// Sequence: guard -> SB -> reg-fence -> [flush] -> phaseA -> phaseB(ds) ->
// consume lv(b-2) -> issue lv(b) -> [stage(b+2) -> ldt(b+2)]
#define GBT_BODY(TB_, BUF_, P_, PRE_, GUARDSTR)                                \
    do {                                                                       \
        const int tb_ = (TB_);                                                 \
        asm volatile("s_waitcnt vmcnt(" GUARDSTR ")" ::: "memory");            \
        __builtin_amdgcn_sched_barrier(0);                                     \
        REG_FENCE(P_);                                                         \
        if (tb_ >= 2 + TILES_PER_CLASS && (tb_ - 2) % TILES_PER_CLASS == 0) {  \
            atomicAdd(&sums[sLocal * SUMS_STRIDE                               \
                            + ((tb_ - 2) / TILES_PER_CLASS - 1)], acc);        \
            acc = 0.f;                                                         \
        }                                                                      \
        int o0_, o1_;                                                          \
        PHASE_A(t##P_##0a, t##P_##0b, t##P_##0c, t##P_##0d, o0_);              \
        PHASE_A(t##P_##1a, t##P_##1b, t##P_##1c, t##P_##1d, o1_);              \
        const int2* nb0_ = &nbuf[BUF_][(j * 2 + 0) * 64];                      \
        const int2* nb1_ = &nbuf[BUF_][(j * 2 + 1) * 64];                      \
        _Pragma("unroll")                                                      \
        for (int d_ = 3; d_ < DEPTH; ++d_) {     /* Phase B: LDS gather */     \
            int2 na_  = nb0_[o0_];               /* ds_read_b64 */             \
            int2 nbv_ = nb1_[o1_];                                             \
            float x0_ = xs[na_.x * SAMPLES_PB + sLocal];                       \
            float x1_ = xs[nbv_.x * SAMPLES_PB + sLocal];                      \
            o0_ = 2 * o0_ + 1 + (x0_ > __int_as_float(na_.y) ? 1 : 0);         \
            o1_ = 2 * o1_ + 1 + (x1_ > __int_as_float(nbv_.y) ? 1 : 0);        \
        }                                                                      \
        acc += lv##P_##0 + lv##P_##1;            /* pair(tb_-2), complete */   \
        {                                                                      \
            const char* lb0__ = (const char*)pleaves                           \
                + ((size_t)(tb_ * T_TILE + j * 2) * 64                         \
                   + (size_t)(o0_ - N_INTERNAL)) * 4;                          \
            const char* lb1__ = (const char*)pleaves                           \
                + ((size_t)(tb_ * T_TILE + j * 2 + 1) * 64                     \
                   + (size_t)(o1_ - N_INTERNAL)) * 4;                          \
            GLD_DW(lv##P_##0, lb0__);                                          \
            GLD_DW(lv##P_##1, lb1__);                                          \
        }                                                                      \
        if (PRE_) {                                                            \
            stage(tb_ + 2, BUF_);                                              \
            LDT_ASM(tb_ + 2, P_);                                              \
        }                                                                      \
    } while (0)

// Fused prep: blocks [0,1024) transpose x into x^T; blocks [1024,2024) pack
// nodes+leaves into class-grouped slots.
__global__ void prep_kernel(const float* __restrict__ x,
                            const int* __restrict__ features,
                            const float* __restrict__ thresholds,
                            const float* __restrict__ leaves,
                            int2* __restrict__ pn, float* __restrict__ pl,
                            float* __restrict__ xt) {
    const int tid = threadIdx.x;
    if (blockIdx.x < XPOSE_BLOCKS) {
        __shared__ float tile[N_FEATURES * 33];
        const int sample0 = blockIdx.x * SAMPLES_PB;
        const float4* xg = (const float4*)(x + (size_t)sample0 * N_FEATURES);
        #pragma unroll
        for (int k = 0; k < 4; ++k) {
            int e = tid + k * BLOCK;
            int s = e >> 5, f4 = e & 31;
            float4 v = xg[e];
            int f = f4 << 2;
            tile[(f + 0) * 33 + s] = v.x;
            tile[(f + 1) * 33 + s] = v.y;
            tile[(f + 2) * 33 + s] = v.z;
            tile[(f + 3) * 33 + s] = v.w;
        }
        __syncthreads();
        #pragma unroll
        for (int k = 0; k < 4; ++k) {
            int e = tid + k * BLOCK;
            int f = e >> 3, sq = e & 7;
            float4 w;
            w.x = tile[f * 33 + 4 * sq + 0];
            w.y = tile[f * 33 + 4 * sq + 1];
            w.z = tile[f * 33 + 4 * sq + 2];
            w.w = tile[f * 33 + 4 * sq + 3];
            *(float4*)(xt + (size_t)f * BATCH + sample0 + 4 * sq) = w;
        }
    } else {
        int i = (blockIdx.x - XPOSE_BLOCKS) * BLOCK + tid;
        int t = i >> 6, n = i & 63;
        int slot = (t % N_CLASSES) * (N_TREES / N_CLASSES) + (t / N_CLASSES);
        if (n < N_INTERNAL)
            pn[slot * 64 + n] = make_int2(features[t * N_INTERNAL + n],
                                          __float_as_int(thresholds[t * N_INTERNAL + n]));
        pl[slot * 64 + n] = leaves[t * 64 + n];
    }
}

// Standalone pack (mid tier without xt space)
__global__ void pack_kernel(const int* __restrict__ features,
                            const float* __restrict__ thresholds,
                            const float* __restrict__ leaves,
                            int2* __restrict__ pn, float* __restrict__ pl) {
    int i = blockIdx.x * blockDim.x + threadIdx.x;
    int t = i >> 6, n = i & 63;
    if (t < N_TREES) {
        int slot = (t % N_CLASSES) * (N_TREES / N_CLASSES) + (t / N_CLASSES);
        if (n < N_INTERNAL)
            pn[slot * 64 + n] = make_int2(features[t * N_INTERNAL + n],
                                          __float_as_int(thresholds[t * N_INTERNAL + n]));
        pl[slot * 64 + n] = leaves[t * 64 + n];
    }
}

// CK-style addrspace casts for global_load_lds (proven R5..R12).
__device__ __forceinline__ void load_lds_16(const void* g, void* l) {
    const auto* g1 = reinterpret_cast<const __attribute__((address_space(1))) uint32_t*>(
        reinterpret_cast<uintptr_t>(g));
    auto* l3 = reinterpret_cast<__attribute__((address_space(3))) uint32_t*>(
        reinterpret_cast<uintptr_t>(l));
    __builtin_amdgcn_global_load_lds(g1, l3, 16, 0, 0);
}

template <bool XT>
__global__ __launch_bounds__(BLOCK, 4) void gbt_eval(
    const float* __restrict__ x,        // original [BATCH][F] (XT=false path)
    const float* __restrict__ xt,       // x^T [F][BATCH]      (XT=true path)
    const int2*  __restrict__ pnodes,   // [N_TREES][64] int2, class-grouped slots
    const float* __restrict__ pleaves,  // [N_TREES][64], class-grouped slots
    const float* __restrict__ init_out, // [10]
    float*       __restrict__ out)      // [BATCH][10], written directly
{
    __shared__ float xs[N_FEATURES * SAMPLES_PB];       // 16 KB, transposed [f][s]
    __shared__ int2  nbuf[2][T_TILE * 64];              // 2 x 8 KB node tiles
    __shared__ float sums[SAMPLES_PB * SUMS_STRIDE];    // 1.4 KB

    const int tid = threadIdx.x;
    const int sample0 = blockIdx.x * SAMPLES_PB;
    const int lane    = tid & 63;
    const int wv      = tid >> 6;       // wave id 0..3 (wave-uniform)

    if (XT) {
        #pragma unroll
        for (int q = 0; q < 4; ++q) {
            int f0 = wv * 32 + q * 8;
            const char* g = (const char*)(xt
                + (size_t)(f0 + (lane >> 3)) * BATCH + sample0 + (lane & 7) * 4);
            load_lds_16(g, (char*)xs + (size_t)f0 * SAMPLES_PB * 4);
        }
    } else {
        const float4* xg = (const float4*)(x + (size_t)sample0 * N_FEATURES);
        for (int e = tid; e < SAMPLES_PB * (N_FEATURES / 4); e += BLOCK) {
            int s = e >> 5, f4 = e & 31;
            float4 v = xg[e];
            int f = f4 << 2;
            xs[(f + 0) * SAMPLES_PB + s] = v.x;
            xs[(f + 1) * SAMPLES_PB + s] = v.y;
            xs[(f + 2) * SAMPLES_PB + s] = v.z;
            xs[(f + 3) * SAMPLES_PB + s] = v.w;
        }
    }
    for (int i = tid; i < SAMPLES_PB * SUMS_STRIDE; i += BLOCK) sums[i] = 0.f;

    // Stage one 8 KB int2 node tile. Wave wv DMAs chunks 2wv,2wv+1 (trees
    // 4wv..4wv+3) -- exactly the trees its own half-waves read: wave-private.
    auto stage = [&](int tile, int b) {
        const char* g = (const char*)(pnodes + (size_t)(tile * T_TILE) * 64);
        char* lbase = (char*)&nbuf[b][0];
        #pragma unroll
        for (int q = 0; q < 2; ++q) {
            int k = wv * 2 + q;
            load_lds_16(g + k * 1024 + lane * 16, lbase + k * 1024);
        }
    };

    const int sLocal = tid & (SAMPLES_PB - 1);
    const int j      = tid >> 5;        // 0..7 half-wave chunks; trees 2j, 2j+1

    // Named opaque register sets (even/odd tile parity).
    i32x4 tE0a, tE0b, tE0c, tE1a, tE1b, tE1c;
    i32x4 tO0a, tO0b, tO0c, tO1a, tO1b, tO1c;
    i32x2 tE0d, tE1d, tO0d, tO1d;
    float lvE0 = 0.f, lvE1 = 0.f, lvO0 = 0.f, lvO1 = 0.f;

    // Prologue: prime buffers + both parity reg sets; barrier drains vmcnt.
    stage(0, 0);
    LDT_ASM(0, E);
    stage(1, 1);
    LDT_ASM(1, O);
    __syncthreads();   // xs cross-wave shared: full barrier (drains vmcnt(0))

    float acc = 0.f;

    // Continuous 250-tile loop: bodies 0..247 in the unroll-2 loop (all
    // prefetch tile+2 <= 249), bodies 248/249 peeled.
    for (int it = 0; it < (N_TILES - 2) / 2; ++it) {       // 124 iterations
        const int b = 2 * it;
        GBT_BODY(b,     0, E, 1, "12");
        GBT_BODY(b + 1, 1, O, 1, "12");
    }
    GBT_BODY(N_TILES - 2, 0, E, 0, "12");
    GBT_BODY(N_TILES - 1, 1, O, 0, "2");

    // Epilogue: drain, consume final pairs (tiles 248, 249 -> class 9).
    asm volatile("s_waitcnt vmcnt(0)" ::: "memory");
    __builtin_amdgcn_sched_barrier(0);
    asm volatile("" : "+v"(lvE0), "+v"(lvE1), "+v"(lvO0), "+v"(lvO1));
    acc += lvE0 + lvE1 + lvO0 + lvO1;
    atomicAdd(&sums[sLocal * SUMS_STRIDE + (N_CLASSES - 1)], acc);
    __syncthreads();

    // Sole owner of these samples: plain coalesced stores, init folded in.
    for (int e = tid; e < SAMPLES_PB * N_CLASSES; e += BLOCK) {
        int s = e / N_CLASSES, k = e - s * N_CLASSES;
        out[(size_t)(sample0 + s) * N_CLASSES + k] =
            init_out[k] + LR * sums[s * SUMS_STRIDE + k];
    }
}

// Fallback (ws too small even for nodes+leaves): direct-global gather.
__global__ __launch_bounds__(BLOCK, 8) void gbt_eval_global(
    const float* __restrict__ x,
    const int*   __restrict__ features,
    const float* __restrict__ thresholds,
    const float* __restrict__ leaf_values,
    const float* __restrict__ init_out,
    float*       __restrict__ out)
{
    __shared__ float xs[N_FEATURES * SAMPLES_PB];
    __shared__ float sums[SAMPLES_PB * N_CLASSES];
    const int tid = threadIdx.x;
    const int sample0 = blockIdx.x * SAMPLES_PB;
    {
        const float4* xg = (const float4*)(x + (size_t)sample0 * N_FEATURES);
        for (int e = tid; e < SAMPLES_PB * (N_FEATURES / 4); e += BLOCK) {
            int s = e >> 5, f4 = e & 31;
            float4 v = xg[e];
            int f = f4 << 2;
            xs[(f + 0) * SAMPLES_PB + s] = v.x;
            xs[(f + 1) * SAMPLES_PB + s] = v.y;
            xs[(f + 2) * SAMPLES_PB + s] = v.z;
            xs[(f + 3) * SAMPLES_PB + s] = v.w;
        }
    }
    for (int i = tid; i < SAMPLES_PB * N_CLASSES; i += BLOCK) sums[i] = 0.f;
    __syncthreads();
    const int sLocal = tid & (SAMPLES_PB - 1);
    const int j = tid >> 5;
    const int TPT = N_TREES / 8;
    const int t0 = j * TPT;
    float acc[N_CLASSES];
    #pragma unroll
    for (int k = 0; k < N_CLASSES; ++k) acc[k] = 0.f;
    for (int i = 0; i < TPT; i += N_CLASSES) {
        const int tt = t0 + i;
        int idx[N_CLASSES];
        #pragma unroll
        for (int u = 0; u < N_CLASSES; ++u) idx[u] = 0;
        #pragma unroll
        for (int d = 0; d < DEPTH; ++d) {
            #pragma unroll
            for (int u = 0; u < N_CLASSES; ++u) {
                int base = (tt + u) * N_INTERNAL + idx[u];
                float xv = xs[features[base] * SAMPLES_PB + sLocal];
                idx[u] = 2 * idx[u] + 1 + (xv > thresholds[base] ? 1 : 0);
            }
        }
        #pragma unroll
        for (int u = 0; u < N_CLASSES; ++u)
            acc[u] += leaf_values[(size_t)(tt + u) * 64 + idx[u] - N_INTERNAL];
    }
    #pragma unroll
    for (int k = 0; k < N_CLASSES; ++k)
        atomicAdd(&sums[sLocal * N_CLASSES + k], acc[k]);
    __syncthreads();
    for (int e = tid; e < SAMPLES_PB * N_CLASSES; e += BLOCK) {
        int s = e / N_CLASSES, k = e - s * N_CLASSES;
        out[(size_t)(sample0 + s) * N_CLASSES + k] = init_out[k] + LR * sums[e];
    }
}

extern "C" void kernel_launch(void* const* d_in, const int* in_sizes, int n_in,
                              void* d_out, int out_size, void* d_ws, size_t ws_size,
                              hipStream_t stream) {
    const float* x          = (const float*)d_in[0];
    const int*   features   = (const int*)d_in[1];
    const float* thresholds = (const float*)d_in[2];
    const float* leafvals   = (const float*)d_in[3];
    const float* init_out   = (const float*)d_in[4];
    float*       out        = (float*)d_out;

    const int grid = BATCH / SAMPLES_PB;    // 1024 = 256 CU x 4 blocks

    if (ws_size >= WS_NODES_BYTES + WS_LEAVES_BYTES + WS_XT_BYTES) {
        int2*  pn = (int2*)d_ws;
        float* pl = (float*)((char*)d_ws + WS_NODES_BYTES);
        float* xt = (float*)((char*)d_ws + WS_NODES_BYTES + WS_LEAVES_BYTES);
        prep_kernel<<<XPOSE_BLOCKS + PACK_BLOCKS, BLOCK, 0, stream>>>(
            x, features, thresholds, leafvals, pn, pl, xt);
        gbt_eval<true><<<grid, BLOCK, 0, stream>>>(x, xt, pn, pl, init_out, out);
    } else if (ws_size >= WS_NODES_BYTES + WS_LEAVES_BYTES) {
        int2*  pn = (int2*)d_ws;
        float* pl = (float*)((char*)d_ws + WS_NODES_BYTES);
        int n = N_TREES * 64;
        pack_kernel<<<(n + 255) / 256, 256, 0, stream>>>(features, thresholds,
                                                         leafvals, pn, pl);
        gbt_eval<false><<<grid, BLOCK, 0, stream>>>(x, nullptr, pn, pl, init_out, out);
    } else {
        gbt_eval_global<<<BATCH / SAMPLES_PB, BLOCK, 0, stream>>>(
            x, features, thresholds, leafvals, init_out, out);
    }
}

// Round 8
// 293.203 us; speedup vs baseline: 1.5215x; 1.5215x over previous
//
#include <hip/hip_runtime.h>
#include <stdint.h>

// Problem constants (from reference)
#define N_CLASSES  10
#define N_TREES    4000
#define DEPTH      6
#define N_INTERNAL 63
#define N_FEATURES 128
#define BATCH      32768
#define LR         0.1f

// Kernel config (R20 = R13 champion eval, transpose tier REMOVED).
// R13's gbt_eval (243us) sits ON the LDS-gather floor: per (sample,tree,
// level) visit = (1 b32 xs + 1 b64 node)/64 lanes ~= 0.2 cyc -> 614K cyc/CU
// ~= 256us model. R14-R19 (six rounds) tried to move top-level node reads
// off the DS pipe via scalar pipe / compiler loads / inline-asm loads; all
// failed identically (prefetch regs never materialized, VGPR stayed 52;
// plus VMEM issue cost ~= DS savings). Remaining win: prep. The xt
// transpose (17MB R + 16MB W, ~40us) exists only to feed global_load_lds
// xs staging; the XT=false path stages xs from row-major x with coalesced
// float4 loads (16KB/block one-time, ~2-3us total) and needs no xt.
// R20: prep = pack only (~3MB, ~3us); eval = gbt_eval<false>, byte-identical
// traversal loop to the 243us champion.
#define BLOCK       256
#define SAMPLES_PB  32
#define T_TILE      16                      // trees per LDS tile (8 KB int2 nodes)
#define N_TILES     (N_TREES / T_TILE)      // 250
#define TILES_PER_CLASS ((N_TREES / N_CLASSES) / T_TILE)   // 25
#define SUMS_STRIDE 11

// ws layout:
//   [0, 2.048MB)        nodes by slot, interleaved int2 (feat, thr_bits), 64/tree
//   [2.048MB, 3.072MB)  leaves (64 f32/tree), class-grouped slots
// slot = (t%10)*400 + t/10  (class-grouped: 25-tile runs are single-class).
#define WS_NODES_BYTES  ((size_t)N_TREES * 64 * 8)
#define WS_LEAVES_BYTES ((size_t)N_TREES * 64 * 4)

// s_waitcnt immediates (gfx9): vmcnt[3:0] | expcnt<<4 | lgkmcnt<<8
#define WAITCNT_VM4  0x0F74    // vmcnt(4): keep 4 newest (lv pair + next DMA pair)
#define WAITCNT_VM2  0x0F72    // vmcnt(2): keep 2 newest (lv pair), last tile

// Pack nodes+leaves into class-grouped slots (the only prep needed).
__global__ void pack_kernel(const int* __restrict__ features,
                            const float* __restrict__ thresholds,
                            const float* __restrict__ leaves,
                            int2* __restrict__ pn, float* __restrict__ pl) {
    int i = blockIdx.x * blockDim.x + threadIdx.x;
    int t = i >> 6, n = i & 63;
    if (t < N_TREES) {
        int slot = (t % N_CLASSES) * (N_TREES / N_CLASSES) + (t / N_CLASSES);
        if (n < N_INTERNAL)
            pn[slot * 64 + n] = make_int2(features[t * N_INTERNAL + n],
                                          __float_as_int(thresholds[t * N_INTERNAL + n]));
        pl[slot * 64 + n] = leaves[t * 64 + n];
    }
}

// CK-style addrspace casts for global_load_lds (proven R5..R12).
__device__ __forceinline__ void load_lds_16(const void* g, void* l) {
    const auto* g1 = reinterpret_cast<const __attribute__((address_space(1))) uint32_t*>(
        reinterpret_cast<uintptr_t>(g));
    auto* l3 = reinterpret_cast<__attribute__((address_space(3))) uint32_t*>(
        reinterpret_cast<uintptr_t>(l));
    __builtin_amdgcn_global_load_lds(g1, l3, 16, 0, 0);
}

template <bool XT>
__global__ __launch_bounds__(BLOCK, 4) void gbt_eval(
    const float* __restrict__ x,        // original [BATCH][F] (XT=false path)
    const float* __restrict__ xt,       // x^T [F][BATCH]      (XT=true path, unused)
    const int2*  __restrict__ pnodes,   // [N_TREES][64] int2, class-grouped slots
    const float* __restrict__ pleaves,  // [N_TREES][64], class-grouped slots
    const float* __restrict__ init_out, // [10]
    float*       __restrict__ out)      // [BATCH][10], written directly
{
    __shared__ float xs[N_FEATURES * SAMPLES_PB];       // 16 KB, transposed [f][s]
    __shared__ int2  nbuf[2][T_TILE * 64];              // 2 x 8 KB node tiles
    __shared__ float sums[SAMPLES_PB * SUMS_STRIDE];    // 1.4 KB

    const int tid = threadIdx.x;
    const int sample0 = blockIdx.x * SAMPLES_PB;
    const int lane    = tid & 63;
    const int wv      = tid >> 6;       // wave id 0..3 (wave-uniform)

    if (XT) {
        #pragma unroll
        for (int q = 0; q < 4; ++q) {
            int f0 = wv * 32 + q * 8;
            const char* g = (const char*)(xt
                + (size_t)(f0 + (lane >> 3)) * BATCH + sample0 + (lane & 7) * 4);
            load_lds_16(g, (char*)xs + (size_t)f0 * SAMPLES_PB * 4);
        }
    } else {
        // Stage xs from row-major x: 16 KB/block, coalesced float4 reads.
        // The loads are consumed by LDS stores before the barrier, so the
        // in-loop vmcnt FIFO accounting below is unaffected.
        const float4* xg = (const float4*)(x + (size_t)sample0 * N_FEATURES);
        for (int e = tid; e < SAMPLES_PB * (N_FEATURES / 4); e += BLOCK) {
            int s = e >> 5, f4 = e & 31;
            float4 v = xg[e];
            int f = f4 << 2;
            xs[(f + 0) * SAMPLES_PB + s] = v.x;
            xs[(f + 1) * SAMPLES_PB + s] = v.y;
            xs[(f + 2) * SAMPLES_PB + s] = v.z;
            xs[(f + 3) * SAMPLES_PB + s] = v.w;
        }
    }
    for (int i = tid; i < SAMPLES_PB * SUMS_STRIDE; i += BLOCK) sums[i] = 0.f;

    // Stage one 8 KB int2 node tile. Wave wv DMAs chunks 2wv,2wv+1 (trees
    // 4wv..4wv+3) -- exactly the trees its own half-waves read: wave-private.
    auto stage = [&](int tile, int b) {
        const char* g = (const char*)(pnodes + (size_t)(tile * T_TILE) * 64);
        char* lbase = (char*)&nbuf[b][0];
        #pragma unroll
        for (int q = 0; q < 2; ++q) {
            int k = wv * 2 + q;
            load_lds_16(g + k * 1024 + lane * 16, lbase + k * 1024);
        }
    };

    stage(0, 0);
    __syncthreads();   // xs is cross-wave shared: one full barrier (drains vmcnt)

    const int sLocal = tid & (SAMPLES_PB - 1);
    const int j      = tid >> 5;        // 0..7 half-wave chunks; trees 2j, 2j+1

    int cur = 0;
    for (int c = 0; c < N_CLASSES; ++c) {
        float acc = 0.f;
        float lv0 = 0.f, lv1 = 0.f;     // previous tile's leaf loads (pipelined)
        for (int t25 = 0; t25 < TILES_PER_CLASS; ++t25) {
            const int tile = c * TILES_PER_CLASS + t25;
            // Issue next-tile DMA, then wait for THIS tile's DMA only:
            // vmcnt(4) keeps {lv pair, next DMA pair} in flight (FIFO order:
            // DMA(t) < lv(t-1) < DMA(t+1)).
            if (tile + 1 < N_TILES) {
                stage(tile + 1, cur ^ 1);
                __builtin_amdgcn_s_waitcnt(WAITCNT_VM4);
            } else {
                __builtin_amdgcn_s_waitcnt(WAITCNT_VM2);
            }

            const int2* nb0 = &nbuf[cur][(j * 2 + 0) * 64];
            const int2* nb1 = &nbuf[cur][(j * 2 + 1) * 64];
            int o0 = 0, o1 = 0;
            #pragma unroll
            for (int d = 0; d < DEPTH; ++d) {
                int2 a = nb0[o0];           // ds_read_b64 (interleaved f,thr)
                int2 b = nb1[o1];
                float x0 = xs[a.x * SAMPLES_PB + sLocal];
                float x1 = xs[b.x * SAMPLES_PB + sLocal];
                o0 = 2 * o0 + 1 + (x0 > __int_as_float(a.y) ? 1 : 0);
                o1 = 2 * o1 + 1 + (x1 > __int_as_float(b.y) ? 1 : 0);
            }
            const size_t slotA = (size_t)(tile * T_TILE + j * 2);
            // Consume PREVIOUS tile's leaves (issued one iteration ago ->
            // latency hidden; they're older than DMA(t+1), so this wait does
            // not drain the prefetch), then issue this tile's leaf loads.
            acc += lv0 + lv1;
            lv0 = pleaves[slotA * 64       + (o0 - N_INTERNAL)];
            lv1 = pleaves[(slotA + 1) * 64 + (o1 - N_INTERNAL)];
            cur ^= 1;
        }
        acc += lv0 + lv1;               // flush the class's final pair
        atomicAdd(&sums[sLocal * SUMS_STRIDE + c], acc);
    }
    __syncthreads();

    // Sole owner of these samples: plain coalesced stores, init folded in.
    for (int e = tid; e < SAMPLES_PB * N_CLASSES; e += BLOCK) {
        int s = e / N_CLASSES, k = e - s * N_CLASSES;
        out[(size_t)(sample0 + s) * N_CLASSES + k] =
            init_out[k] + LR * sums[s * SUMS_STRIDE + k];
    }
}

// Fallback (ws too small even for nodes+leaves): direct-global gather,
// single block per 32 samples owns all trees (no atomics on out).
__global__ __launch_bounds__(BLOCK, 8) void gbt_eval_global(
    const float* __restrict__ x,
    const int*   __restrict__ features,
    const float* __restrict__ thresholds,
    const float* __restrict__ leaf_values,
    const float* __restrict__ init_out,
    float*       __restrict__ out)
{
    __shared__ float xs[N_FEATURES * SAMPLES_PB];
    __shared__ float sums[SAMPLES_PB * N_CLASSES];
    const int tid = threadIdx.x;
    const int sample0 = blockIdx.x * SAMPLES_PB;
    {
        const float4* xg = (const float4*)(x + (size_t)sample0 * N_FEATURES);
        for (int e = tid; e < SAMPLES_PB * (N_FEATURES / 4); e += BLOCK) {
            int s = e >> 5, f4 = e & 31;
            float4 v = xg[e];
            int f = f4 << 2;
            xs[(f + 0) * SAMPLES_PB + s] = v.x;
            xs[(f + 1) * SAMPLES_PB + s] = v.y;
            xs[(f + 2) * SAMPLES_PB + s] = v.z;
            xs[(f + 3) * SAMPLES_PB + s] = v.w;
        }
    }
    for (int i = tid; i < SAMPLES_PB * N_CLASSES; i += BLOCK) sums[i] = 0.f;
    __syncthreads();
    const int sLocal = tid & (SAMPLES_PB - 1);
    const int j = tid >> 5;
    const int TPT = N_TREES / 8;
    const int t0 = j * TPT;
    float acc[N_CLASSES];
    #pragma unroll
    for (int k = 0; k < N_CLASSES; ++k) acc[k] = 0.f;
    for (int i = 0; i < TPT; i += N_CLASSES) {
        const int tt = t0 + i;
        int idx[N_CLASSES];
        #pragma unroll
        for (int u = 0; u < N_CLASSES; ++u) idx[u] = 0;
        #pragma unroll
        for (int d = 0; d < DEPTH; ++d) {
            #pragma unroll
            for (int u = 0; u < N_CLASSES; ++u) {
                int base = (tt + u) * N_INTERNAL + idx[u];
                float xv = xs[features[base] * SAMPLES_PB + sLocal];
                idx[u] = 2 * idx[u] + 1 + (xv > thresholds[base] ? 1 : 0);
            }
        }
        #pragma unroll
        for (int u = 0; u < N_CLASSES; ++u)
            acc[u] += leaf_values[(size_t)(tt + u) * 64 + idx[u] - N_INTERNAL];
    }
    #pragma unroll
    for (int k = 0; k < N_CLASSES; ++k)
        atomicAdd(&sums[sLocal * N_CLASSES + k], acc[k]);
    __syncthreads();
    for (int e = tid; e < SAMPLES_PB * N_CLASSES; e += BLOCK) {
        int s = e / N_CLASSES, k = e - s * N_CLASSES;
        out[(size_t)(sample0 + s) * N_CLASSES + k] = init_out[k] + LR * sums[e];
    }
}

extern "C" void kernel_launch(void* const* d_in, const int* in_sizes, int n_in,
                              void* d_out, int out_size, void* d_ws, size_t ws_size,
                              hipStream_t stream) {
    const float* x          = (const float*)d_in[0];
    const int*   features   = (const int*)d_in[1];
    const float* thresholds = (const float*)d_in[2];
    const float* leafvals   = (const float*)d_in[3];
    const float* init_out   = (const float*)d_in[4];
    float*       out        = (float*)d_out;

    const int grid = BATCH / SAMPLES_PB;    // 1024 = 256 CU x 4 blocks

    if (ws_size >= WS_NODES_BYTES + WS_LEAVES_BYTES) {
        // Pack-only prep (~3MB); eval stages xs from row-major x directly.
        int2*  pn = (int2*)d_ws;
        float* pl = (float*)((char*)d_ws + WS_NODES_BYTES);
        int n = N_TREES * 64;
        pack_kernel<<<(n + 255) / 256, 256, 0, stream>>>(features, thresholds,
                                                         leafvals, pn, pl);
        gbt_eval<false><<<grid, BLOCK, 0, stream>>>(x, nullptr, pn, pl, init_out, out);
    } else {
        gbt_eval_global<<<BATCH / SAMPLES_PB, BLOCK, 0, stream>>>(
            x, features, thresholds, leafvals, init_out, out);
    }
}